// Round 8
// baseline (1719.721 us; speedup 1.0000x reference)
//
#include <hip/hip_runtime.h>
#include <hip/hip_bf16.h>
#include <hip/hip_fp16.h>

// ManualRNN: B=32, T=2048, Fin=256, H=256, O=256  (all f32 in/out)
//   phase1: xh = x @ Wxh^T + bxh   -> stored f32 in d_out's y region (dead before phase3)
//   phase2: h_t = tanh(xh_t + h @ Whh^T), scan over T -> hs f16 in d_ws
//   phase3: y  = hs @ Why^T + by   -> overwrites y region
// h_final (32x256 f32) at d_out + 65536*256.
//
// r8: VALU-matvec scan, diagnostic rebuild. r6 (fdot2) and r7 (explicit fma)
// failed with BIT-IDENTICAL absmax 2.992188 -> the dot primitive is NOT the
// bug; suspect is the float2->f16-pack + bit_cast(u32x4/half2v) data path
// (the only constructs never used in a passing kernel). This round removes
// them: wreg via cvt8 (the GEMMs' verified helper), dot via direct
// ext-vector element access + fmaf chains (v_fma_mix_f32, f32 accumulate).
// hreg loads / shfl_xor(32) / publish / barrier identical to r7.
// r5 lesson: LDS spin-poll >=120cy on critical path -> s_barrier
// (lgkmcnt-only drain) is the right per-step sync.

typedef _Float16 f16x8  __attribute__((ext_vector_type(8)));
typedef float    f32x4  __attribute__((ext_vector_type(4)));

#define MFMA16 __builtin_amdgcn_mfma_f32_16x16x32_f16

__device__ __forceinline__ f16x8 cvt8(const float* __restrict__ p) {
    float4 u = *(const float4*)p;
    float4 v = *(const float4*)(p + 4);
    f16x8 r;
    r[0] = (_Float16)u.x; r[1] = (_Float16)u.y; r[2] = (_Float16)u.z; r[3] = (_Float16)u.w;
    r[4] = (_Float16)v.x; r[5] = (_Float16)v.y; r[6] = (_Float16)v.z; r[7] = (_Float16)v.w;
    return r;
}

// C[m][n] = sum_k A[m][k] * W[n][k] + bias[n];  M = gridDim.x*64, N = K = 256.
template<bool AF16>
__global__ __launch_bounds__(256, 2) void gemm_nt_256(
    const void* __restrict__ Av, const float* __restrict__ W,
    const float* __restrict__ bias, float* __restrict__ C) {
    const int tid = threadIdx.x;
    const int l  = tid & 63;
    const int w  = tid >> 6;
    const int lr = l & 15;
    const int lg = l >> 4;
    const long m0 = (long)blockIdx.x * 64;
    const int  n0 = w * 64;

    f32x4 acc[4][4] = {};

    #pragma unroll
    for (int k = 0; k < 8; ++k) {
        const int kc = k * 32 + lg * 8;
        f16x8 a[4], bf[4];
        #pragma unroll
        for (int mt = 0; mt < 4; ++mt) {
            const long row = m0 + mt * 16 + lr;
            if constexpr (AF16)
                a[mt] = *(const f16x8*)((const _Float16*)Av + row * 256 + kc);
            else
                a[mt] = cvt8((const float*)Av + row * 256 + kc);
        }
        #pragma unroll
        for (int nt = 0; nt < 4; ++nt)
            bf[nt] = cvt8(W + (long)(n0 + nt * 16 + lr) * 256 + kc);
        #pragma unroll
        for (int mt = 0; mt < 4; ++mt)
            #pragma unroll
            for (int nt = 0; nt < 4; ++nt)
                acc[mt][nt] = MFMA16(a[mt], bf[nt], acc[mt][nt], 0, 0, 0);
    }

    #pragma unroll
    for (int mt = 0; mt < 4; ++mt)
        #pragma unroll
        for (int nt = 0; nt < 4; ++nt) {
            const int col = n0 + nt * 16 + lr;
            const float bv = bias[col];
            #pragma unroll
            for (int d = 0; d < 4; ++d) {
                const long row = m0 + mt * 16 + lg * 4 + d;
                C[row * 256 + col] = acc[mt][nt][d] + bv;
            }
        }
}

// Recurrence (VALU version): 32 blocks (1 batch) x 512 threads (8 waves).
// Lane owns (col = w*32 + (l&31), k-half = l>>5). Whh[col][half*128..+128]
// as 16x f16x8 in VGPRs (loaded via cvt8). Per step: 16x ds_read_b128 of h
// (broadcast), 128 fmaf (v_fma_mix_f32, 4 chains), shfl_xor(32) k-half
// reduce, tanh, publish. LDS-only barrier; xh prefetched 4 steps deep.
__global__ __launch_bounds__(512, 1) void rnn_scan(
    const float* __restrict__ xh, const float* __restrict__ h0,
    const float* __restrict__ Whh, _Float16* __restrict__ hs,
    float* __restrict__ hfin) {
    const int b    = blockIdx.x;
    const int tid  = threadIdx.x;
    const int l    = tid & 63;
    const int w    = tid >> 6;      // 0..7
    const int col  = w * 32 + (l & 31);
    const int half = l >> 5;        // k in [half*128, half*128+128)

    __shared__ _Float16 hbuf[2][256];

    // wreg8[i] = (f16) Whh[col][half*128 + 8i .. +8]   (64 VGPR, via cvt8)
    f16x8 wreg8[16];
    {
        const float* wp = Whh + (long)col * 256 + half * 128;
        #pragma unroll
        for (int i = 0; i < 16; ++i) wreg8[i] = cvt8(wp + 8 * i);
    }

    if (tid < 256) hbuf[0][tid] = (_Float16)h0[b * 256 + tid];
    __syncthreads();

    const float* xp = xh + (long)b * 2048 * 256 + col;
    _Float16*    hp = hs + (long)b * 2048 * 256 + col;

    float xcur[4], xnext[4];
    #pragma unroll
    for (int j = 0; j < 4; ++j) xcur[j] = xp[(long)j * 256];

    for (int tb = 0; tb < 2048; tb += 4) {
        // next group's xh loads: ~2500cy cover >> 900cy HBM latency
        #pragma unroll
        for (int j = 0; j < 4; ++j) {
            long tn = tb + 4 + j; if (tn > 2047) tn = 2047;
            xnext[j] = xp[tn * 256];
        }

        #pragma unroll
        for (int j = 0; j < 4; ++j) {
            const int t = tb + j;                       // t&1 == j&1

            // h fragment: 16 x ds_read_b128 (2 distinct addrs/instr = free 2-way bcast)
            const f16x8* hc = (const f16x8*)hbuf[j & 1] + half * 16;
            f16x8 hreg[16];
            #pragma unroll
            for (int i = 0; i < 16; ++i) hreg[i] = hc[i];

            // 128 mixed-precision FMAs, 4 independent chains, no bit_casts
            float s0 = 0.f, s1 = 0.f, s2 = 0.f, s3 = 0.f;
            #pragma unroll
            for (int i = 0; i < 16; ++i) {
                const f16x8 h8 = hreg[i];
                const f16x8 w8 = wreg8[i];
                s0 = fmaf((float)h8[0], (float)w8[0], s0);
                s0 = fmaf((float)h8[1], (float)w8[1], s0);
                s1 = fmaf((float)h8[2], (float)w8[2], s1);
                s1 = fmaf((float)h8[3], (float)w8[3], s1);
                s2 = fmaf((float)h8[4], (float)w8[4], s2);
                s2 = fmaf((float)h8[5], (float)w8[5], s2);
                s3 = fmaf((float)h8[6], (float)w8[6], s3);
                s3 = fmaf((float)h8[7], (float)w8[7], s3);
            }
            float s = (s0 + s1) + (s2 + s3);

            // pair-reduce across k-halves (lanes l <-> l^32 share a col)
            s += __shfl_xor(s, 32, 64);

            // tanh(s + xh) = 1 - 2/(exp(2s)+1)
            const float sx = s + xcur[j];
            const float e  = __expf(2.0f * sx);
            const float v  = 1.0f - 2.0f * __builtin_amdgcn_rcpf(e + 1.0f);
            const _Float16 hv = (_Float16)v;

            if (l < 32) {
                hbuf[(j & 1) ^ 1][col] = hv;            // next step's h
                hp[(long)t * 256] = hv;                 // fire-and-forget hs
                if (t == 2047) hfin[b * 256 + col] = v;
            }

            // LDS-only barrier (no vmcnt drain)
            asm volatile("s_waitcnt lgkmcnt(0)" ::: "memory");
            __builtin_amdgcn_s_barrier();
            asm volatile("" ::: "memory");
        }

        #pragma unroll
        for (int j = 0; j < 4; ++j) xcur[j] = xnext[j];
    }
}

extern "C" void kernel_launch(void* const* d_in, const int* in_sizes, int n_in,
                              void* d_out, int out_size, void* d_ws, size_t ws_size,
                              hipStream_t stream) {
    const float* x   = (const float*)d_in[0];
    const float* h0  = (const float*)d_in[1];
    const float* Wxh = (const float*)d_in[2];
    const float* bxh = (const float*)d_in[3];
    const float* Whh = (const float*)d_in[4];
    const float* Why = (const float*)d_in[5];
    const float* by  = (const float*)d_in[6];

    float* y    = (float*)d_out;
    float* hfin = y + (long)65536 * 256;
    float* xh   = y;                       // xh scratch aliases y (dead before phase3 writes)
    _Float16* hs = (_Float16*)d_ws;

    gemm_nt_256<false><<<1024, 256, 0, stream>>>(x, Wxh, bxh, xh);
    rnn_scan<<<32, 512, 0, stream>>>(xh, h0, Whh, hs, hfin);
    gemm_nt_256<true><<<1024, 256, 0, stream>>>(hs, Why, by, y);
}

// Round 9
// 1604.293 us; speedup vs baseline: 1.0719x; 1.0719x over previous
//
#include <hip/hip_runtime.h>
#include <hip/hip_fp16.h>

// ManualRNN: B=32, T=2048, Fin=256, H=256, O=256 (all f32 in/out)
// SINGLE fused kernel, 32 blocks (1 per batch) x 512 threads (8 waves):
//   boot : xh = x@Wxh^T + bxh  (dense-M GEMM, this batch's 2048 rows) -> d_out y region
//   scan : h_t = tanh(xh_t + h@Whh^T)  (r4 MFMA body verbatim, 819us verified)
//          + y-slice trickle: 1 MFMA/step of y = hs@Why^T + by, 128-step lag,
//            riding the ~337cy/step idle MFMA/epilogue window
//   tail : last 9 y row-tiles
// hs (f16) in d_ws; h_final at d_out + 65536*256.
//
// History: r4 = MFMA scan 957cy/step (620 MFMA pipe + 337 serial chain).
// r5 flags regressed (LDS poll latency); r6/r7 failed on a f16-pack/bit_cast
// bug; r8 VALU path = 1877cy/step (compiler emits cvt+fma, no fma_mix) -> dead.
// All register arrays statically indexed (rule #20): wg/pya slices selected
// via uniform switch on (tb>>2)&3 with constant indices.

typedef _Float16 f16x8 __attribute__((ext_vector_type(8)));
typedef float    f32x4 __attribute__((ext_vector_type(4)));

#define MFMA16 __builtin_amdgcn_mfma_f32_16x16x32_f16

__device__ __forceinline__ f16x8 cvt8(const float* __restrict__ p) {
    float4 u = *(const float4*)p;
    float4 v = *(const float4*)(p + 4);
    f16x8 r;
    r[0] = (_Float16)u.x; r[1] = (_Float16)u.y; r[2] = (_Float16)u.z; r[3] = (_Float16)u.w;
    r[4] = (_Float16)v.x; r[5] = (_Float16)v.y; r[6] = (_Float16)v.z; r[7] = (_Float16)v.w;
    return r;
}

__global__ __launch_bounds__(512, 1) void rnn_fused(
    const float* __restrict__ x,   const float* __restrict__ h0,
    const float* __restrict__ Wxh, const float* __restrict__ bxh,
    const float* __restrict__ Whh, const float* __restrict__ Why,
    const float* __restrict__ by,
    float* __restrict__ xy,        // d_out: xh scratch, then y (65536x256 f32)
    float* __restrict__ hfin,      // d_out + 65536*256
    _Float16* __restrict__ hs) {   // d_ws: (2048*32)x256 f16
    const int b   = blockIdx.x;
    const int tid = threadIdx.x;
    const int l   = tid & 63;
    const int w   = tid >> 6;      // 0..7
    const int lr  = l & 15;
    const int lg  = l >> 4;
    const int n0  = w * 32;
    const int cl  = n0 + (l & 31);

    __shared__ _Float16 hbuf[2][256];

    const float* xb  = x  + (long)b * 2048 * 256;
    float*       xyb = xy + (long)b * 2048 * 256;
    _Float16*    hpB = hs + (long)b * 2048 * 256;

    // Whh fragments, resident across the whole kernel
    f16x8 wb[2][8];
    #pragma unroll
    for (int nt = 0; nt < 2; ++nt)
        #pragma unroll
        for (int k = 0; k < 8; ++k)
            wb[nt][k] = cvt8(Whh + (long)(n0 + nt * 16 + lr) * 256 + k * 32 + lg * 8);

    // Phase-shared GEMM fragments: Wxh during boot, reloaded with Why for scan/tail
    f16x8 wg[2][8];
    #pragma unroll
    for (int nt = 0; nt < 2; ++nt)
        #pragma unroll
        for (int k = 0; k < 8; ++k)
            wg[nt][k] = cvt8(Wxh + (long)(n0 + nt * 16 + lr) * 256 + k * 32 + lg * 8);

    if (tid < 256) hbuf[0][tid] = (_Float16)h0[b * 256 + tid];

    // ---- boot: xh = x@Wxh^T + bxh, dense M (this batch's 2048 rows) ----
    for (int mt = 0; mt < 128; ++mt) {
        f32x4 ac[2] = {{0.f,0.f,0.f,0.f},{0.f,0.f,0.f,0.f}};
        #pragma unroll
        for (int k = 0; k < 8; ++k) {
            const int kc = k * 32 + lg * 8;
            f16x8 a = cvt8(xb + (long)(mt * 16 + lr) * 256 + kc);
            ac[0] = MFMA16(a, wg[0][k], ac[0], 0, 0, 0);
            ac[1] = MFMA16(a, wg[1][k], ac[1], 0, 0, 0);
        }
        #pragma unroll
        for (int nt = 0; nt < 2; ++nt) {
            const int col = n0 + nt * 16 + lr;
            const float bv = bxh[col];
            #pragma unroll
            for (int d = 0; d < 4; ++d)
                xyb[(long)(mt * 16 + lg * 4 + d) * 256 + col] = ac[nt][d] + bv;
        }
    }

    // swap wg -> Why fragments (register reuse, disjoint lifetime)
    #pragma unroll
    for (int nt = 0; nt < 2; ++nt)
        #pragma unroll
        for (int k = 0; k < 8; ++k)
            wg[nt][k] = cvt8(Why + (long)(n0 + nt * 16 + lr) * 256 + k * 32 + lg * 8);

    __syncthreads();   // drains vmcnt: xh stores visible; hbuf ready

    const float* xp = xyb + cl;
    _Float16*    hp = hpB + cl;

    float xcur[4], xnext[4];
    #pragma unroll
    for (int j = 0; j < 4; ++j) xcur[j] = xp[(long)j * 256];

    f32x4 sacc[2] = {{0.f,0.f,0.f,0.f},{0.f,0.f,0.f,0.f}};  // y-slice acc
    f16x8 pya[4];                                            // y A-frag prefetch

#define YS(P, K)                                               \
    do {                                                       \
        sacc[0] = MFMA16(pya[P], wg[0][K], sacc[0], 0, 0, 0);  \
        sacc[1] = MFMA16(pya[P], wg[1][K], sacc[1], 0, 0, 0);  \
    } while (0)

    for (int tb = 0; tb < 2048; tb += 4) {
        const int g = tb >> 4;
        const int m = g - 8;                       // y row-tile, 128-step lag
        const bool yact = (m >= 0) && (m <= 118);  // 119..127 in tail

        // y A-frag prefetch: k0..3 at group top, k4..7 at half-group (hs is
        // L2-hot: same block wrote it >=113 steps ago)
        if (yact && (tb & 15) == 0) {
            const _Float16* ap = hpB + (long)(m * 16 + lr) * 256 + lg * 8;
            pya[0] = *(const f16x8*)(ap);
            pya[1] = *(const f16x8*)(ap + 32);
            pya[2] = *(const f16x8*)(ap + 64);
            pya[3] = *(const f16x8*)(ap + 96);
        }
        if (yact && (tb & 15) == 8) {
            const _Float16* ap = hpB + (long)(m * 16 + lr) * 256 + 128 + lg * 8;
            pya[0] = *(const f16x8*)(ap);
            pya[1] = *(const f16x8*)(ap + 32);
            pya[2] = *(const f16x8*)(ap + 64);
            pya[3] = *(const f16x8*)(ap + 96);
        }

        // next group's xh loads: ~2500cy cover >> 900cy HBM latency
        #pragma unroll
        for (int j = 0; j < 4; ++j) {
            long tn = tb + 4 + j; if (tn > 2047) tn = 2047;
            xnext[j] = xp[tn * 256];
        }

        #pragma unroll
        for (int j = 0; j < 4; ++j) {
            const int t = tb + j;                       // t&1 == j&1
            const f16x8* hc = (const f16x8*)hbuf[j & 1];
            f16x8 af[8];
            #pragma unroll
            for (int k = 0; k < 8; ++k) af[k] = hc[k * 4 + lg];
            __builtin_amdgcn_sched_barrier(0);

            const f32x4 zero = {0.f, 0.f, 0.f, 0.f};
            f32x4 accA[2], accB[2];                     // split chains k0-3 / k4-7
            #pragma unroll
            for (int nt = 0; nt < 2; ++nt) {
                accA[nt] = MFMA16(af[0], wb[nt][0], zero, 0, 0, 0);
                accB[nt] = MFMA16(af[4], wb[nt][4], zero, 0, 0, 0);
            }
            #pragma unroll
            for (int k = 1; k < 4; ++k)
                #pragma unroll
                for (int nt = 0; nt < 2; ++nt) {
                    accA[nt] = MFMA16(af[k],     wb[nt][k],     accA[nt], 0, 0, 0);
                    accB[nt] = MFMA16(af[k + 4], wb[nt][k + 4], accB[nt], 0, 0, 0);
                }

            // tanh(s + xh) = 1 - 2/(exp(2s)+1); select col's sum first
            const float s0 = accA[0][0] + accB[0][0];
            const float s1 = accA[1][0] + accB[1][0];
            const float s  = ((l & 16) ? s1 : s0) + xcur[j];
            const float e  = __expf(2.0f * s);
            const float v  = 1.0f - 2.0f * __builtin_amdgcn_rcpf(e + 1.0f);
            const _Float16 hv = (_Float16)v;

            if (l < 32) {
                hbuf[(j & 1) ^ 1][cl] = hv;              // next step's h
                hp[(long)t * 256] = hv;                  // fire-and-forget hs
                if (t == 2047) hfin[b * 256 + cl] = v;
            }

            // y-slice: 2 MFMAs issued into the barrier-wait window.
            // Static indices via uniform switch (rule #20).
            if (j == 1 && yact) {
                switch ((tb >> 2) & 3) {
                    case 0: YS(0, 0); break;
                    case 1: YS(2, 2); break;
                    case 2: YS(0, 4); break;
                    case 3: YS(2, 6); break;
                }
            }
            if (j == 3 && yact) {
                switch ((tb >> 2) & 3) {
                    case 0: YS(1, 1); break;
                    case 1: YS(3, 3); break;
                    case 2: YS(1, 5); break;
                    case 3: YS(3, 7); break;
                }
            }

            // LDS-only barrier (no vmcnt drain)
            asm volatile("s_waitcnt lgkmcnt(0)" ::: "memory");
            __builtin_amdgcn_s_barrier();
            asm volatile("" ::: "memory");
        }

        // y writeout at group end (rows long dead for xh reads)
        if (yact && (tb & 15) == 12) {
            #pragma unroll
            for (int nt = 0; nt < 2; ++nt) {
                const int col = n0 + nt * 16 + lr;
                const float bv = by[col];
                #pragma unroll
                for (int d = 0; d < 4; ++d)
                    xyb[(long)(m * 16 + lg * 4 + d) * 256 + col] = sacc[nt][d] + bv;
                sacc[nt] = (f32x4){0.f, 0.f, 0.f, 0.f};
            }
        }

        #pragma unroll
        for (int j = 0; j < 4; ++j) xcur[j] = xnext[j];
    }

    // ---- tail: y row-tiles 119..127 (needs the last hs rows) ----
    __syncthreads();   // vmcnt drain: all waves' hs stores visible
    for (int mt = 119; mt < 128; ++mt) {
        f32x4 ac[2] = {{0.f,0.f,0.f,0.f},{0.f,0.f,0.f,0.f}};
        #pragma unroll
        for (int k = 0; k < 8; ++k) {
            const int kc = k * 32 + lg * 8;
            f16x8 a = *(const f16x8*)(hpB + (long)(mt * 16 + lr) * 256 + kc);
            ac[0] = MFMA16(a, wg[0][k], ac[0], 0, 0, 0);
            ac[1] = MFMA16(a, wg[1][k], ac[1], 0, 0, 0);
        }
        #pragma unroll
        for (int nt = 0; nt < 2; ++nt) {
            const int col = n0 + nt * 16 + lr;
            const float bv = by[col];
            #pragma unroll
            for (int d = 0; d < 4; ++d)
                xyb[(long)(mt * 16 + lg * 4 + d) * 256 + col] = ac[nt][d] + bv;
        }
    }
#undef YS
}

extern "C" void kernel_launch(void* const* d_in, const int* in_sizes, int n_in,
                              void* d_out, int out_size, void* d_ws, size_t ws_size,
                              hipStream_t stream) {
    const float* x   = (const float*)d_in[0];
    const float* h0  = (const float*)d_in[1];
    const float* Wxh = (const float*)d_in[2];
    const float* bxh = (const float*)d_in[3];
    const float* Whh = (const float*)d_in[4];
    const float* Why = (const float*)d_in[5];
    const float* by  = (const float*)d_in[6];

    float* y    = (float*)d_out;
    float* hfin = y + (long)65536 * 256;
    _Float16* hs = (_Float16*)d_ws;

    rnn_fused<<<32, 512, 0, stream>>>(x, h0, Wxh, bxh, Whh, Why, by, y, hfin, hs);
}

// Round 10
// 920.204 us; speedup vs baseline: 1.8688x; 1.7434x over previous
//
#include <hip/hip_runtime.h>
#include <hip/hip_fp16.h>

// ManualRNN: B=32, T=2048, Fin=256, H=256, O=256 (all f32 in/out)
//   phase1: xh(f16) = x @ Wxh^T + bxh  -> second half of d_out y region (33.5MB)
//   phase2: h_t = tanh(xh_t + h@Whh^T) scan (r3 structure, 819us verified) -> hs f16 in d_ws
//   phase3: y(f32) = hs @ Why^T + by   -> d_out (rows>=32768 overwrite dead xh)
// h_final at d_out + 65536*256.
//
// Ledger: scan floor = 620cy issue (128 MFMA/block-step, config-invariant:
// batch-packing/interleave don't reduce per-block-step issue) + ~337cy serial
// (tanh chain + ds_write/lgkm + barrier + ds_read latency). r5 flags: poll
// latency > barrier. r8 VALU: cvt+fma codegen 3x worse. r9 y-trickle: register
// pressure (>=190 VGPR demand) wrecked scan codegen -> scan must stay lean.
// r10: GEMMs get M128 tiles (B-frags amortized 8x) + f16 xh write.

typedef _Float16 f16x8 __attribute__((ext_vector_type(8)));
typedef float    f32x4 __attribute__((ext_vector_type(4)));

#define MFMA16 __builtin_amdgcn_mfma_f32_16x16x32_f16

__device__ __forceinline__ f16x8 cvt8(const float* __restrict__ p) {
    float4 u = *(const float4*)p;
    float4 v = *(const float4*)(p + 4);
    f16x8 r;
    r[0] = (_Float16)u.x; r[1] = (_Float16)u.y; r[2] = (_Float16)u.z; r[3] = (_Float16)u.w;
    r[4] = (_Float16)v.x; r[5] = (_Float16)v.y; r[6] = (_Float16)v.z; r[7] = (_Float16)v.w;
    return r;
}

// C[m][n] = sum_k A[m][k]*W[n][k] + bias[n];  M-tile 128, N=K=256.
// 512 thr / 8 waves; wave w owns 32 cols (2 n-tiles); B-frags loaded ONCE
// (64 VGPR), then 8 m-tiles stream through. 512 blocks for M=65536.
template<bool AF16, bool OF16>
__global__ __launch_bounds__(512, 2) void gemm_nt_512(
    const void* __restrict__ Av, const float* __restrict__ W,
    const float* __restrict__ bias, void* __restrict__ Cv) {
    const int tid = threadIdx.x;
    const int l  = tid & 63;
    const int w  = tid >> 6;        // 0..7
    const int lr = l & 15;
    const int lg = l >> 4;
    const long m0 = (long)blockIdx.x * 128;
    const int  n0 = w * 32;

    f16x8 wg[2][8];
    #pragma unroll
    for (int nt = 0; nt < 2; ++nt)
        #pragma unroll
        for (int k = 0; k < 8; ++k)
            wg[nt][k] = cvt8(W + (long)(n0 + nt * 16 + lr) * 256 + k * 32 + lg * 8);

    const float bv0 = bias[n0 + lr];
    const float bv1 = bias[n0 + 16 + lr];

    #pragma unroll 2
    for (int mt = 0; mt < 8; ++mt) {
        const long r0 = m0 + mt * 16 + lr;
        f32x4 ac[2] = {{0.f,0.f,0.f,0.f},{0.f,0.f,0.f,0.f}};
        #pragma unroll
        for (int k = 0; k < 8; ++k) {
            const int kc = k * 32 + lg * 8;
            f16x8 a;
            if constexpr (AF16) a = *(const f16x8*)((const _Float16*)Av + r0 * 256 + kc);
            else                a = cvt8((const float*)Av + r0 * 256 + kc);
            ac[0] = MFMA16(a, wg[0][k], ac[0], 0, 0, 0);
            ac[1] = MFMA16(a, wg[1][k], ac[1], 0, 0, 0);
        }
        #pragma unroll
        for (int nt = 0; nt < 2; ++nt) {
            const int col = n0 + nt * 16 + lr;
            const float bv = nt ? bv1 : bv0;
            #pragma unroll
            for (int d = 0; d < 4; ++d) {
                const long row = m0 + mt * 16 + lg * 4 + d;
                const float v = ac[nt][d] + bv;
                if constexpr (OF16) ((_Float16*)Cv)[row * 256 + col] = (_Float16)v;
                else                ((float*)Cv)[row * 256 + col] = v;
            }
        }
    }
}

// Recurrence: r3 structure verbatim (819us verified), xh reads f16,
// s_setprio around the MFMA cluster. 32 blocks x 512 thr (8 waves).
__global__ __launch_bounds__(512, 1) void rnn_scan(
    const _Float16* __restrict__ xh, const float* __restrict__ h0,
    const float* __restrict__ Whh, _Float16* __restrict__ hs,
    float* __restrict__ hfin) {
    const int b   = blockIdx.x;
    const int tid = threadIdx.x;
    const int l   = tid & 63;
    const int w   = tid >> 6;   // 0..7
    const int lr  = l & 15;
    const int lg  = l >> 4;
    const int n0  = w * 32;

    __shared__ _Float16 hbuf[2][256];

    f16x8 wb[2][8];
    #pragma unroll
    for (int nt = 0; nt < 2; ++nt)
        #pragma unroll
        for (int k = 0; k < 8; ++k)
            wb[nt][k] = cvt8(Whh + (long)(n0 + nt * 16 + lr) * 256 + k * 32 + lg * 8);

    if (tid < 256) hbuf[0][tid] = (_Float16)h0[b * 256 + tid];
    __syncthreads();

    const int cl = n0 + (l & 31);
    const _Float16* xp = xh + (long)b * 2048 * 256 + cl;
    _Float16*       hp = hs + (long)b * 2048 * 256 + cl;

    float xcur[4], xnext[4];
    #pragma unroll
    for (int j = 0; j < 4; ++j) xcur[j] = (float)xp[(long)j * 256];

    for (int tb = 0; tb < 2048; tb += 4) {
        // next group's xh loads: ~2500cy cover >> 900cy HBM latency
        #pragma unroll
        for (int j = 0; j < 4; ++j) {
            long tn = tb + 4 + j; if (tn > 2047) tn = 2047;
            xnext[j] = (float)xp[tn * 256];
        }

        #pragma unroll
        for (int j = 0; j < 4; ++j) {
            const f16x8* hc = (const f16x8*)hbuf[j & 1];   // t&1 == j&1
            f16x8 af[8];
            #pragma unroll
            for (int k = 0; k < 8; ++k) af[k] = hc[k * 4 + lg];

            __builtin_amdgcn_s_setprio(1);
            const f32x4 zero = {0.f, 0.f, 0.f, 0.f};
            f32x4 accA[2], accB[2];              // split chains k0-3 / k4-7
            #pragma unroll
            for (int nt = 0; nt < 2; ++nt) {
                accA[nt] = MFMA16(af[0], wb[nt][0], zero, 0, 0, 0);
                accB[nt] = MFMA16(af[4], wb[nt][4], zero, 0, 0, 0);
            }
            #pragma unroll
            for (int k = 1; k < 4; ++k)
                #pragma unroll
                for (int nt = 0; nt < 2; ++nt) {
                    accA[nt] = MFMA16(af[k],     wb[nt][k],     accA[nt], 0, 0, 0);
                    accB[nt] = MFMA16(af[k + 4], wb[nt][k + 4], accB[nt], 0, 0, 0);
                }
            __builtin_amdgcn_s_setprio(0);

            // single tanh chain: select col's sum first
            const float s0 = accA[0][0] + accB[0][0];
            const float s1 = accA[1][0] + accB[1][0];
            const float s  = ((l & 16) ? s1 : s0) + xcur[j];
            const float e  = __expf(2.0f * s);
            const float v  = 1.0f - 2.0f * __builtin_amdgcn_rcpf(e + 1.0f);
            const _Float16 hv = (_Float16)v;

            if (l < 32) {
                hbuf[(j & 1) ^ 1][cl] = hv;              // next step's h
                hp[(long)(tb + j) * 256] = hv;           // fire-and-forget
            }

            // LDS-only barrier (no vmcnt drain)
            asm volatile("s_waitcnt lgkmcnt(0)" ::: "memory");
            __builtin_amdgcn_s_barrier();
            asm volatile("" ::: "memory");
        }

        #pragma unroll
        for (int j = 0; j < 4; ++j) xcur[j] = xnext[j];
    }

    // t=2047 wrote parity ((2047&1)^1)=0
    if (tid < 256) hfin[b * 256 + tid] = (float)hbuf[0][tid];
}

extern "C" void kernel_launch(void* const* d_in, const int* in_sizes, int n_in,
                              void* d_out, int out_size, void* d_ws, size_t ws_size,
                              hipStream_t stream) {
    const float* x   = (const float*)d_in[0];
    const float* h0  = (const float*)d_in[1];
    const float* Wxh = (const float*)d_in[2];
    const float* bxh = (const float*)d_in[3];
    const float* Whh = (const float*)d_in[4];
    const float* Why = (const float*)d_in[5];
    const float* by  = (const float*)d_in[6];

    float* y    = (float*)d_out;                   // (65536,256) f32
    float* hfin = y + (long)65536 * 256;           // (32,256) f32
    // xh f16 (33.5MB) in the SECOND HALF of the y region: dead before phase3
    // writes rows >= 32768 there.
    _Float16* xhf = (_Float16*)(y + (long)32768 * 256);
    _Float16* hs  = (_Float16*)d_ws;               // (65536,256) f16

    // phase1: xh(f16) = x @ Wxh^T + bxh
    gemm_nt_512<false, true ><<<512, 512, 0, stream>>>(x, Wxh, bxh, xhf);
    // phase2: scan
    rnn_scan<<<32, 512, 0, stream>>>(xhf, h0, Whh, hs, hfin);
    // phase3: y(f32) = hs @ Why^T + by
    gemm_nt_512<true,  false><<<512, 512, 0, stream>>>(hs, Why, by, y);
}

// Round 11
// 919.631 us; speedup vs baseline: 1.8700x; 1.0006x over previous
//
#include <hip/hip_runtime.h>
#include <hip/hip_fp16.h>

// ManualRNN: B=32, T=2048, Fin=256, H=256, O=256 (all f32 in/out)
//   phase1: xh(f16) = x @ Wxh^T + bxh  -> second half of d_out y region (33.5MB)
//           epilogue via per-wave LDS transpose -> 64B-aligned f16x8 stores
//   phase2: h_t = tanh(xh_t + h@Whh^T) scan (r10 body verbatim, 799us) -> hs f16 in d_ws
//   phase3: y(f32) = hs @ Why^T + by   -> d_out (rows>=32768 overwrite dead xh)
// h_final at d_out + 65536*256.
//
// Ledger: scan step = 933cy = 620cy MFMA issue floor (128 MFMA/block-step,
// config-invariant) + ~313cy serial tail (true data dependency h->s->h: the
// recurrence is a global sync per step; barrier is the cheapest sync - r5
// flags cost more). r8: VALU path 2x worse (cvt+fma codegen). r9: y-trickle
// register pressure caused remat/re-fetch (85GB FETCH) - scan must stay lean.
// r10: GEMM budget ~121us constant across configs; BW floor ~40us. This
// round: phase1 32B partial-line f16 stores -> LDS-transposed 64B line stores.

typedef _Float16 f16x8 __attribute__((ext_vector_type(8)));
typedef float    f32x4 __attribute__((ext_vector_type(4)));

#define MFMA16 __builtin_amdgcn_mfma_f32_16x16x32_f16

__device__ __forceinline__ f16x8 cvt8(const float* __restrict__ p) {
    float4 u = *(const float4*)p;
    float4 v = *(const float4*)(p + 4);
    f16x8 r;
    r[0] = (_Float16)u.x; r[1] = (_Float16)u.y; r[2] = (_Float16)u.z; r[3] = (_Float16)u.w;
    r[4] = (_Float16)v.x; r[5] = (_Float16)v.y; r[6] = (_Float16)v.z; r[7] = (_Float16)v.w;
    return r;
}

// C[m][n] = sum_k A[m][k]*W[n][k] + bias[n];  M-tile 128, N=K=256.
// 512 thr / 8 waves; wave w owns 32 cols; B-frags loaded once (64 VGPR).
// OF16: f16 output staged through per-wave LDS transpose so global writes are
// 64B-aligned 16B/lane segments (direct path would be 32B partial lines).
template<bool AF16, bool OF16>
__global__ __launch_bounds__(512, 2) void gemm_nt_512(
    const void* __restrict__ Av, const float* __restrict__ W,
    const float* __restrict__ bias, void* __restrict__ Cv) {
    const int tid = threadIdx.x;
    const int l  = tid & 63;
    const int w  = tid >> 6;        // 0..7
    const int lr = l & 15;
    const int lg = l >> 4;
    const long m0 = (long)blockIdx.x * 128;
    const int  n0 = w * 32;

    __shared__ _Float16 st[8][16][40];   // [wave][row][32 cols + pad]

    f16x8 wg[2][8];
    #pragma unroll
    for (int nt = 0; nt < 2; ++nt)
        #pragma unroll
        for (int k = 0; k < 8; ++k)
            wg[nt][k] = cvt8(W + (long)(n0 + nt * 16 + lr) * 256 + k * 32 + lg * 8);

    const float bv0 = bias[n0 + lr];
    const float bv1 = bias[n0 + 16 + lr];

    #pragma unroll 2
    for (int mt = 0; mt < 8; ++mt) {
        const long r0 = m0 + mt * 16 + lr;
        f32x4 ac[2] = {{0.f,0.f,0.f,0.f},{0.f,0.f,0.f,0.f}};
        #pragma unroll
        for (int k = 0; k < 8; ++k) {
            const int kc = k * 32 + lg * 8;
            f16x8 a;
            if constexpr (AF16) a = *(const f16x8*)((const _Float16*)Av + r0 * 256 + kc);
            else                a = cvt8((const float*)Av + r0 * 256 + kc);
            ac[0] = MFMA16(a, wg[0][k], ac[0], 0, 0, 0);
            ac[1] = MFMA16(a, wg[1][k], ac[1], 0, 0, 0);
        }
        if constexpr (OF16) {
            // per-wave LDS transpose: scatter f16, read back row-contiguous
            #pragma unroll
            for (int nt = 0; nt < 2; ++nt) {
                const float bv = nt ? bv1 : bv0;
                #pragma unroll
                for (int d = 0; d < 4; ++d)
                    st[w][lg * 4 + d][nt * 16 + lr] = (_Float16)(ac[nt][d] + bv);
            }
            asm volatile("s_waitcnt lgkmcnt(0)" ::: "memory");
            const int row = l >> 2;         // 0..15
            const int q   = l & 3;          // 16B quarter
            f16x8 vv = *(const f16x8*)&st[w][row][q * 8];
            *( f16x8*)((_Float16*)Cv + (m0 + mt * 16 + row) * 256 + n0 + q * 8) = vv;
            asm volatile("s_waitcnt lgkmcnt(0)" ::: "memory");  // read done before next mt's writes
        } else {
            #pragma unroll
            for (int nt = 0; nt < 2; ++nt) {
                const int col = n0 + nt * 16 + lr;
                const float bv = nt ? bv1 : bv0;
                #pragma unroll
                for (int d = 0; d < 4; ++d) {
                    const long row = m0 + mt * 16 + lg * 4 + d;
                    ((float*)Cv)[row * 256 + col] = ac[nt][d] + bv;
                }
            }
        }
    }
}

// Recurrence: r10 body verbatim (799us verified). 32 blocks x 512 thr (8 waves).
__global__ __launch_bounds__(512, 1) void rnn_scan(
    const _Float16* __restrict__ xh, const float* __restrict__ h0,
    const float* __restrict__ Whh, _Float16* __restrict__ hs,
    float* __restrict__ hfin) {
    const int b   = blockIdx.x;
    const int tid = threadIdx.x;
    const int l   = tid & 63;
    const int w   = tid >> 6;   // 0..7
    const int lr  = l & 15;
    const int lg  = l >> 4;
    const int n0  = w * 32;

    __shared__ _Float16 hbuf[2][256];

    f16x8 wb[2][8];
    #pragma unroll
    for (int nt = 0; nt < 2; ++nt)
        #pragma unroll
        for (int k = 0; k < 8; ++k)
            wb[nt][k] = cvt8(Whh + (long)(n0 + nt * 16 + lr) * 256 + k * 32 + lg * 8);

    if (tid < 256) hbuf[0][tid] = (_Float16)h0[b * 256 + tid];
    __syncthreads();

    const int cl = n0 + (l & 31);
    const _Float16* xp = xh + (long)b * 2048 * 256 + cl;
    _Float16*       hp = hs + (long)b * 2048 * 256 + cl;

    float xcur[4], xnext[4];
    #pragma unroll
    for (int j = 0; j < 4; ++j) xcur[j] = (float)xp[(long)j * 256];

    for (int tb = 0; tb < 2048; tb += 4) {
        // next group's xh loads: ~2500cy cover >> 900cy HBM latency
        #pragma unroll
        for (int j = 0; j < 4; ++j) {
            long tn = tb + 4 + j; if (tn > 2047) tn = 2047;
            xnext[j] = (float)xp[tn * 256];
        }

        #pragma unroll
        for (int j = 0; j < 4; ++j) {
            const f16x8* hc = (const f16x8*)hbuf[j & 1];   // t&1 == j&1
            f16x8 af[8];
            #pragma unroll
            for (int k = 0; k < 8; ++k) af[k] = hc[k * 4 + lg];

            __builtin_amdgcn_s_setprio(1);
            const f32x4 zero = {0.f, 0.f, 0.f, 0.f};
            f32x4 accA[2], accB[2];              // split chains k0-3 / k4-7
            #pragma unroll
            for (int nt = 0; nt < 2; ++nt) {
                accA[nt] = MFMA16(af[0], wb[nt][0], zero, 0, 0, 0);
                accB[nt] = MFMA16(af[4], wb[nt][4], zero, 0, 0, 0);
            }
            #pragma unroll
            for (int k = 1; k < 4; ++k)
                #pragma unroll
                for (int nt = 0; nt < 2; ++nt) {
                    accA[nt] = MFMA16(af[k],     wb[nt][k],     accA[nt], 0, 0, 0);
                    accB[nt] = MFMA16(af[k + 4], wb[nt][k + 4], accB[nt], 0, 0, 0);
                }
            __builtin_amdgcn_s_setprio(0);

            // single tanh chain: select col's sum first
            const float s0 = accA[0][0] + accB[0][0];
            const float s1 = accA[1][0] + accB[1][0];
            const float s  = ((l & 16) ? s1 : s0) + xcur[j];
            const float e  = __expf(2.0f * s);
            const float v  = 1.0f - 2.0f * __builtin_amdgcn_rcpf(e + 1.0f);
            const _Float16 hv = (_Float16)v;

            if (l < 32) {
                hbuf[(j & 1) ^ 1][cl] = hv;              // next step's h
                hp[(long)(tb + j) * 256] = hv;           // fire-and-forget
            }

            // LDS-only barrier (no vmcnt drain)
            asm volatile("s_waitcnt lgkmcnt(0)" ::: "memory");
            __builtin_amdgcn_s_barrier();
            asm volatile("" ::: "memory");
        }

        #pragma unroll
        for (int j = 0; j < 4; ++j) xcur[j] = xnext[j];
    }

    // t=2047 wrote parity ((2047&1)^1)=0
    if (tid < 256) hfin[b * 256 + tid] = (float)hbuf[0][tid];
}

extern "C" void kernel_launch(void* const* d_in, const int* in_sizes, int n_in,
                              void* d_out, int out_size, void* d_ws, size_t ws_size,
                              hipStream_t stream) {
    const float* x   = (const float*)d_in[0];
    const float* h0  = (const float*)d_in[1];
    const float* Wxh = (const float*)d_in[2];
    const float* bxh = (const float*)d_in[3];
    const float* Whh = (const float*)d_in[4];
    const float* Why = (const float*)d_in[5];
    const float* by  = (const float*)d_in[6];

    float* y    = (float*)d_out;                   // (65536,256) f32
    float* hfin = y + (long)65536 * 256;           // (32,256) f32
    // xh f16 (33.5MB) in the SECOND HALF of the y region: dead before phase3
    // writes rows >= 32768 there.
    _Float16* xhf = (_Float16*)(y + (long)32768 * 256);
    _Float16* hs  = (_Float16*)d_ws;               // (65536,256) f16

    // phase1: xh(f16) = x @ Wxh^T + bxh   (LDS-transposed 64B-line stores)
    gemm_nt_512<false, true ><<<512, 512, 0, stream>>>(x, Wxh, bxh, xhf);
    // phase2: scan
    rnn_scan<<<32, 512, 0, stream>>>(xhf, h0, Whh, hs, hfin);
    // phase3: y(f32) = hs @ Why^T + by
    gemm_nt_512<true,  false><<<512, 512, 0, stream>>>(hs, Why, by, y);
}